// Round 1
// baseline (347.075 us; speedup 1.0000x reference)
//
#include <hip/hip_runtime.h>
#include <hip/hip_bf16.h>

#define B_SZ 512
#define I_SZ 7
#define D_SZ 512
#define J_SZ 64
#define E_SZ 128
#define N_SZ 8192
#define ITERS 10

typedef __attribute__((ext_vector_type(8))) short bf16x8;
typedef __attribute__((ext_vector_type(4))) float f32x4;

#if defined(__has_builtin)
#if __has_builtin(__builtin_amdgcn_cvt_pk_bf16_f32)
#define HAVE_CVT_PK_BF16 1
#endif
#endif

// Split a PAIR of fp32 into packed-bf16 hi and lo words (RNE both stages).
// hp low short = bf16(x0), high short = bf16(x1); same for lp with residuals.
__device__ inline void split2(float x0, float x1, unsigned& hp, unsigned& lp) {
#ifdef HAVE_CVT_PK_BF16
    auto h = __builtin_amdgcn_cvt_pk_bf16_f32(x0, x1);
    hp = __builtin_bit_cast(unsigned, h);
    union { unsigned u; float f; } b0, b1;
    b0.u = hp << 16;
    b1.u = hp & 0xFFFF0000u;
    auto l = __builtin_amdgcn_cvt_pk_bf16_f32(x0 - b0.f, x1 - b1.f);
    lp = __builtin_bit_cast(unsigned, l);
#else
    union { float f; unsigned u; } u0, u1;
    u0.f = x0; u1.f = x1;
    unsigned r0 = u0.u + 0x7FFF + ((u0.u >> 16) & 1);
    unsigned r1 = u1.u + 0x7FFF + ((u1.u >> 16) & 1);
    hp = __builtin_amdgcn_perm(r1, r0, 0x07060302);   // [r1.hi16 | r0.hi16]
    union { unsigned u; float f; } h0, h1;
    h0.u = r0 & 0xFFFF0000u;
    h1.u = r1 & 0xFFFF0000u;
    union { float f; unsigned u; } s0, s1;
    s0.f = x0 - h0.f; s1.f = x1 - h1.f;
    unsigned q0 = s0.u + 0x7FFF + ((s0.u >> 16) & 1);
    unsigned q1 = s1.u + 0x7FFF + ((s1.u >> 16) & 1);
    lp = __builtin_amdgcn_perm(q1, q0, 0x07060302);
#endif
}

// Async global->LDS, 16 B per lane. LDS dest must be wave-uniform base + lane*16
// (our per-thread dest is exactly base + th*16, so each wave's slice is linear).
__device__ inline void gload16(const float* g, float* l) {
    __builtin_amdgcn_global_load_lds(
        (const __attribute__((address_space(1))) void*)g,
        (__attribute__((address_space(3))) void*)l, 16, 0, 0);
}

// ---------------------------------------------------------------------------
// Kernel 1 (R6): vote GEMM, 256x256 tile, BK=32, 512 threads (8 waves x 128x64).
// fW[b,i,j,e] = sum_d f[b,i,d]*W[i,d,j,e].  Per i: C[512,8192]=A[512,512]*B.
// Staging: BOTH operands staged as raw fp32 via global_load_lds (width 16),
// double-buffered (2 x 64 KiB slots = 128 KiB LDS, 1 block/CU, 2 waves/SIMD).
// hi/lo bf16 split happens IN REGISTERS on the fragment path (hides under MFMA).
// acc += Ahi*Bhi + Ahi*Blo + Alo*Bhi  (lo*lo dropped, same math as R5).
// XOR chunk swizzles (applied to stage SOURCE addr and READ addr — rule 21):
//   A[m][k] fp32, 8x16B chunks/row:  pos = chunk ^ (m&7)      -> b128 reads at floor
//   B[k][n] fp32, 64x16B chunks/row: pos = chunk ^ (((k>>3)&1)<<2) -> b32 reads 2/bank
// Pipeline per K-tile: reads -> lgkmcnt(0) -> barrier -> stage t+2 into freed
// slot -> vmcnt(8) (counted, never 0 in-loop) -> barrier.  setprio around MFMA.
// ---------------------------------------------------------------------------
__global__ __launch_bounds__(512) void vote_gemm_mfma(
    const float* __restrict__ f,   // [B, I, D]
    const float* __restrict__ W,   // [I, D, N]
    float* __restrict__ fW)        // [B, I, N]
{
    const int i  = blockIdx.z;
    const int m0 = blockIdx.y * 256;
    const int n0 = blockIdx.x * 256;
    const int th = threadIdx.x;
    const int lane = th & 63;
    const int wave = th >> 6;
    const int wr  = wave >> 2;     // 0..1: 128-row half
    const int wc  = wave & 3;      // 0..3: 64-col quarter
    const int q   = lane >> 4;     // 0..3: k-frag group
    const int l15 = lane & 15;

    __shared__ float ldsA[2][256 * 32];   // [slot][m-major, chunk-swizzled]  32 KiB
    __shared__ float ldsB[2][32 * 256];   // [slot][k-major, chunk-swizzled]  32 KiB

    // ---- per-thread staging source pointers (advance 32 k per tile) ----
    const float* aSrc[4];
    const float* bSrc[4];
#pragma unroll
    for (int ci = 0; ci < 4; ++ci) {
        const int ia = ci * 512 + th;
        const int mA = ia >> 3, sA = ia & 7;                 // row, 16B-chunk slot
        aSrc[ci] = f + (size_t)(m0 + mA) * (I_SZ * D_SZ) + (size_t)i * D_SZ
                     + ((sA ^ (mA & 7)) << 2);               // inverse-swizzled source
        const int ib = ci * 512 + th;
        const int kB = ib >> 6, cB = ib & 63;                // row, 16B-chunk slot
        bSrc[ci] = W + (size_t)i * D_SZ * N_SZ + (size_t)kB * N_SZ + n0
                     + ((cB ^ ((kB & 8) >> 1)) << 2);        // inverse-swizzled source
    }

    auto stage = [&](int slot) {
#pragma unroll
        for (int ci = 0; ci < 4; ++ci)
            gload16(aSrc[ci], &ldsA[slot][(ci * 512 + th) * 4]);
#pragma unroll
        for (int ci = 0; ci < 4; ++ci)
            gload16(bSrc[ci], &ldsB[slot][(ci * 512 + th) * 4]);
#pragma unroll
        for (int ci = 0; ci < 4; ++ci) {
            aSrc[ci] += 32;                 // next 32 k of f row
            bSrc[ci] += (size_t)32 * N_SZ;  // next 32 k-rows of W
        }
    };

    f32x4 acc[8][4];
#pragma unroll
    for (int a = 0; a < 8; ++a)
#pragma unroll
        for (int c = 0; c < 4; ++c)
            acc[a][c] = (f32x4){0.f, 0.f, 0.f, 0.f};

    // ---- prologue: tiles 0,1 in flight; certify tile 0 ----
    stage(0);
    stage(1);
    asm volatile("s_waitcnt vmcnt(8)" ::: "memory");
    __builtin_amdgcn_s_barrier();
    asm volatile("" ::: "memory");

    for (int t = 0; t < 16; ++t) {
        const int slot = t & 1;
        const float* Ab = &ldsA[slot][0];
        const float* Bb = &ldsB[slot][0];

        // ---- B fragments: per-lane column gather (conflict-free b32), split once ----
        uint4 Bh4[4], Bl4[4];
#pragma unroll
        for (int ns = 0; ns < 4; ++ns) {
            const int cs = (wc * 16 + ns * 4 + (l15 >> 2)) ^ ((q & 1) << 2);
            const float* bp = Bb + q * 8 * 256 + cs * 4 + (l15 & 3);
            const float b0 = bp[0 * 256], b1 = bp[1 * 256], b2 = bp[2 * 256], b3 = bp[3 * 256];
            const float b4 = bp[4 * 256], b5 = bp[5 * 256], b6 = bp[6 * 256], b7 = bp[7 * 256];
            split2(b0, b1, Bh4[ns].x, Bl4[ns].x);
            split2(b2, b3, Bh4[ns].y, Bl4[ns].y);
            split2(b4, b5, Bh4[ns].z, Bl4[ns].z);
            split2(b6, b7, Bh4[ns].w, Bl4[ns].w);
        }

        // ---- A pipeline: read 32B -> split -> 12 MFMA per m-subtile ----
#pragma unroll
        for (int ms = 0; ms < 8; ++ms) {
            const int mrow = wr * 128 + ms * 16 + l15;
            const int p0 = (q * 2) ^ (l15 & 7);
            const float4 va = *(const float4*)(Ab + mrow * 32 + ((p0 ^ 0) << 2));
            const float4 vb = *(const float4*)(Ab + mrow * 32 + ((p0 ^ 1) << 2));
            uint4 ah, al;
            split2(va.x, va.y, ah.x, al.x);
            split2(va.z, va.w, ah.y, al.y);
            split2(vb.x, vb.y, ah.z, al.z);
            split2(vb.z, vb.w, ah.w, al.w);
            const bf16x8 Ah = __builtin_bit_cast(bf16x8, ah);
            const bf16x8 Al = __builtin_bit_cast(bf16x8, al);
            __builtin_amdgcn_s_setprio(1);
#pragma unroll
            for (int ns = 0; ns < 4; ++ns) {
                const bf16x8 Bh = __builtin_bit_cast(bf16x8, Bh4[ns]);
                const bf16x8 Bl = __builtin_bit_cast(bf16x8, Bl4[ns]);
                acc[ms][ns] = __builtin_amdgcn_mfma_f32_16x16x32_bf16(Ah, Bh, acc[ms][ns], 0, 0, 0);
                acc[ms][ns] = __builtin_amdgcn_mfma_f32_16x16x32_bf16(Ah, Bl, acc[ms][ns], 0, 0, 0);
                acc[ms][ns] = __builtin_amdgcn_mfma_f32_16x16x32_bf16(Al, Bh, acc[ms][ns], 0, 0, 0);
            }
            __builtin_amdgcn_s_setprio(0);
        }

        // ---- all my reads of this slot done -> slot free for everyone ----
        asm volatile("s_waitcnt lgkmcnt(0)" ::: "memory");
        __builtin_amdgcn_s_barrier();
        asm volatile("" ::: "memory");
        // ---- refill freed slot with tile t+2; certify tile t+1 (counted) ----
        if (t < 14) {
            stage(slot);
            asm volatile("s_waitcnt vmcnt(8)" ::: "memory");
        } else {
            asm volatile("s_waitcnt vmcnt(0)" ::: "memory");
        }
        __builtin_amdgcn_s_barrier();
        asm volatile("" ::: "memory");
    }

    // ---- write C: D layout col=lane&15, row=quad*4+reg (verified in R5) ----
#pragma unroll
    for (int ms = 0; ms < 8; ++ms) {
        const int rowb = m0 + wr * 128 + ms * 16 + q * 4;
#pragma unroll
        for (int ns = 0; ns < 4; ++ns) {
            const int col = n0 + wc * 64 + ns * 16 + l15;
#pragma unroll
            for (int r = 0; r < 4; ++r)
                fW[((size_t)(rowb + r) * I_SZ + i) * N_SZ + col] = acc[ms][ns][r];
        }
    }
}

// ---------------------------------------------------------------------------
// Kernel 2: routing via Gram matrices (unchanged — near floor).
// ---------------------------------------------------------------------------
__global__ __launch_bounds__(1024) void routing_kernel(
    const float* __restrict__ fW,  // [B, I, N]
    const float* __restrict__ p,   // [B, I]
    float* __restrict__ c_out,     // [B, J, E]
    float* __restrict__ r_out)     // [B, I, J]
{
    const int b   = blockIdx.x;
    const int tid = threadIdx.x;
    const int j   = tid >> 4;      // 0..63
    const int sub = tid & 15;      // e-chunk [sub*8, sub*8+8)

    __shared__ float G_sh[64][49];
    __shared__ float s_sh[64][9];
    __shared__ float w_sh[2][64][9];
    __shared__ float p_sh[8];

    if (tid < I_SZ) p_sh[tid] = p[(size_t)b * I_SZ + tid];

    float4 fw[I_SZ][2];
    const float* base = fW + (size_t)b * I_SZ * N_SZ + j * E_SZ + sub * 8;
#pragma unroll
    for (int i = 0; i < I_SZ; ++i) {
        fw[i][0] = *(const float4*)(base + (size_t)i * N_SZ);
        fw[i][1] = *(const float4*)(base + (size_t)i * N_SZ + 4);
    }

    // ---- Phase 1: Gram + row sums (reduce over 16 sub-lanes) ----
#pragma unroll
    for (int i = 0; i < I_SZ; ++i) {
        float s = fw[i][0].x + fw[i][0].y + fw[i][0].z + fw[i][0].w
                + fw[i][1].x + fw[i][1].y + fw[i][1].z + fw[i][1].w;
        s += __shfl_xor(s, 1); s += __shfl_xor(s, 2);
        s += __shfl_xor(s, 4); s += __shfl_xor(s, 8);
        if (sub == 0) s_sh[j][i] = s;
#pragma unroll
        for (int i2 = i; i2 < I_SZ; ++i2) {
            float g = fw[i][0].x * fw[i2][0].x + fw[i][0].y * fw[i2][0].y
                    + fw[i][0].z * fw[i2][0].z + fw[i][0].w * fw[i2][0].w
                    + fw[i][1].x * fw[i2][1].x + fw[i][1].y * fw[i2][1].y
                    + fw[i][1].z * fw[i2][1].z + fw[i][1].w * fw[i2][1].w;
            g += __shfl_xor(g, 1); g += __shfl_xor(g, 2);
            g += __shfl_xor(g, 4); g += __shfl_xor(g, 8);
            if (sub == 0) { G_sh[j][i * 7 + i2] = g; G_sh[j][i2 * 7 + i] = g; }
        }
    }
    __syncthreads();

    // ---- Phase 2: 10 iterations on the 7x7 system ----
    for (int t = 0; t < ITERS; ++t) {
        if (tid < I_SZ * 64) {                 // waves 0..6
            const int ii = tid >> 6;
            const int jj = tid & 63;
            float l;
            if (t == 0) {
                l = s_sh[jj][ii];              // c0 = ones
            } else {
                const int rb = t & 1;
                l = 0.f;
#pragma unroll
                for (int i2 = 0; i2 < I_SZ; ++i2)
                    l = fmaf(w_sh[rb][jj][i2], G_sh[jj][ii * 7 + i2], l);
            }
            float mx = l;
#pragma unroll
            for (int off = 32; off > 0; off >>= 1)
                mx = fmaxf(mx, __shfl_xor(mx, off));
            float ex = __expf(l - mx);
            float sm = ex;
#pragma unroll
            for (int off = 32; off > 0; off >>= 1)
                sm += __shfl_xor(sm, off);
            float r = ex / sm;
            if (t == ITERS - 1)
                r_out[(size_t)b * (I_SZ * J_SZ) + ii * 64 + jj] = r;
            w_sh[(t + 1) & 1][jj][ii] = p_sh[ii] * r;
        }
        __syncthreads();
    }

    // ---- Phase 3: c from registers ----
    float4 a0 = make_float4(0.f, 0.f, 0.f, 0.f);
    float4 a1 = make_float4(0.f, 0.f, 0.f, 0.f);
#pragma unroll
    for (int i = 0; i < I_SZ; ++i) {
        float wv = w_sh[ITERS & 1][j][i];
        a0.x = fmaf(wv, fw[i][0].x, a0.x); a0.y = fmaf(wv, fw[i][0].y, a0.y);
        a0.z = fmaf(wv, fw[i][0].z, a0.z); a0.w = fmaf(wv, fw[i][0].w, a0.w);
        a1.x = fmaf(wv, fw[i][1].x, a1.x); a1.y = fmaf(wv, fw[i][1].y, a1.y);
        a1.z = fmaf(wv, fw[i][1].z, a1.z); a1.w = fmaf(wv, fw[i][1].w, a1.w);
    }
    float* dst = c_out + (size_t)b * N_SZ + j * E_SZ + sub * 8;
    *(float4*)(dst)     = a0;
    *(float4*)(dst + 4) = a1;
}

extern "C" void kernel_launch(void* const* d_in, const int* in_sizes, int n_in,
                              void* d_out, int out_size, void* d_ws, size_t ws_size,
                              hipStream_t stream) {
    const float* f = (const float*)d_in[0];   // [512,7,512]
    const float* p = (const float*)d_in[1];   // [512,7]
    const float* W = (const float*)d_in[2];   // [7,512,64,128]
    float* out = (float*)d_out;               // c (512*64*128) then r (512*7*64)
    float* fW  = (float*)d_ws;                // 117.4 MB scratch

    vote_gemm_mfma<<<dim3(N_SZ / 256, B_SZ / 256, I_SZ), 512, 0, stream>>>(f, W, fW);
    routing_kernel<<<B_SZ, 1024, 0, stream>>>(fW, p, out, out + (size_t)B_SZ * N_SZ);
}

// Round 2
// 309.236 us; speedup vs baseline: 1.1224x; 1.1224x over previous
//
#include <hip/hip_runtime.h>
#include <hip/hip_bf16.h>

#define B_SZ 512
#define I_SZ 7
#define D_SZ 512
#define J_SZ 64
#define E_SZ 128
#define N_SZ 8192
#define ITERS 10

typedef __attribute__((ext_vector_type(8))) short bf16x8;
typedef __attribute__((ext_vector_type(4))) float f32x4;

#if defined(__has_builtin)
#if __has_builtin(__builtin_amdgcn_cvt_pk_bf16_f32)
#define HAVE_CVT_PK_BF16 1
#endif
#endif

// Split a PAIR of fp32 into packed-bf16 hi and lo words (RNE both stages).
// hp low short = bf16(x0), high short = bf16(x1); same for lp with residuals.
__device__ inline void split2(float x0, float x1, unsigned& hp, unsigned& lp) {
#ifdef HAVE_CVT_PK_BF16
    auto h = __builtin_amdgcn_cvt_pk_bf16_f32(x0, x1);
    hp = __builtin_bit_cast(unsigned, h);
    union { unsigned u; float f; } b0, b1;
    b0.u = hp << 16;
    b1.u = hp & 0xFFFF0000u;
    auto l = __builtin_amdgcn_cvt_pk_bf16_f32(x0 - b0.f, x1 - b1.f);
    lp = __builtin_bit_cast(unsigned, l);
#else
    union { float f; unsigned u; } u0, u1;
    u0.f = x0; u1.f = x1;
    unsigned r0 = u0.u + 0x7FFF + ((u0.u >> 16) & 1);
    unsigned r1 = u1.u + 0x7FFF + ((u1.u >> 16) & 1);
    hp = __builtin_amdgcn_perm(r1, r0, 0x07060302);   // [r1.hi16 | r0.hi16]
    union { unsigned u; float f; } h0, h1;
    h0.u = r0 & 0xFFFF0000u;
    h1.u = r1 & 0xFFFF0000u;
    union { float f; unsigned u; } s0, s1;
    s0.f = x0 - h0.f; s1.f = x1 - h1.f;
    unsigned q0 = s0.u + 0x7FFF + ((s0.u >> 16) & 1);
    unsigned q1 = s1.u + 0x7FFF + ((s1.u >> 16) & 1);
    lp = __builtin_amdgcn_perm(q1, q0, 0x07060302);
#endif
}

// ---------------------------------------------------------------------------
// Kernel 1 (R7): vote GEMM, 256x256 tile, BK=32, 512 threads (8 waves x 128x64).
// fW[b,i,j,e] = sum_d f[b,i,d]*W[i,d,j,e].  Per i: C[512,8192]=A[512,512]*B.
// Back to SPLIT-AT-STAGING (once per element): LDS holds 4 bf16 planes
// (Ahi/Alo [m][k], Bhi/Blo [n][k]), double-buffered (2 x 64 KiB = 128 KiB,
// 1 block/CU, 8 waves = 2/SIMD).  Fragments are direct ds_read_b128.
// acc += Ahi*Bhi + Ahi*Blo + Alo*Bhi  (lo*lo dropped, same math as R5/R6).
//
// Per tile (ONE barrier):
//   1. issue t+1 global loads into regs (T14 issue-early)
//   2. B frags (8 b128) + ms 0..5 fragment reads + MFMA    } MFMA hides
//   3. vmcnt-wait (compiler) + 16 split2 + 8 b128 ds_write } global latency
//   4. ms 6..7 fragment reads + MFMA
//   5. __syncthreads (drains own lgkm; slot swap)
// sched_barrier(0) fences pin 1|2, 3, 4 ordering; setprio(1) around MFMA.
//
// LDS XOR swizzle (reg-staged: applied on BOTH write and read — rule 21):
//   row stride 32 shorts (64 B, no pad); 8-short chunk c stored at position
//   c ^ (2*(row&1) | ((row>>1)&1)).  Verified: staging writes and fragment
//   reads each land 8 lanes per 4-bank group tiling all 32 banks (b128 floor).
// ---------------------------------------------------------------------------
__global__ __launch_bounds__(512, 2) void vote_gemm_mfma(
    const float* __restrict__ f,   // [B, I, D]
    const float* __restrict__ W,   // [I, D, N]
    float* __restrict__ fW)        // [B, I, N]
{
    const int i  = blockIdx.z;
    const int m0 = blockIdx.y * 256;
    const int n0 = blockIdx.x * 256;
    const int th = threadIdx.x;
    const int lane = th & 63;
    const int wave = th >> 6;
    const int wr   = wave >> 2;    // 0..1: 128-row half
    const int wc   = wave & 3;     // 0..3: 64-col quarter
    const int quad = lane >> 4;    // 0..3: k-chunk of the fragment
    const int lm   = lane & 15;

    __shared__ short Ah_s[2][256 * 32];
    __shared__ short Al_s[2][256 * 32];
    __shared__ short Bh_s[2][256 * 32];
    __shared__ short Bl_s[2][256 * 32];

    // ---- staging map: thread -> (row sm, k-half kh); same for A and B ----
    const int sm = th >> 1;        // A row m / B col n, 0..255
    const int kh = th & 1;         // 16-k half
    const int swzw = ((sm & 1) << 1) | ((sm >> 1) & 1);
    const int wo0 = sm * 32 + (((kh << 1) | 0) ^ swzw) * 8;   // chunk 2kh
    const int wo1 = sm * 32 + (((kh << 1) | 1) ^ swzw) * 8;   // chunk 2kh+1

    const float* aPtr = f + (size_t)(m0 + sm) * (I_SZ * D_SZ) + (size_t)i * D_SZ + kh * 16;
    const float* bPtr = W + (size_t)i * D_SZ * N_SZ + (size_t)(kh * 16) * N_SZ + n0 + sm;

    // ---- fragment read chunk position (same swizzle, row bits from lm) ----
    const int fpos8 = (quad ^ (((lm & 1) << 1) | ((lm >> 1) & 1))) * 8;

    f32x4 acc[8][4];
#pragma unroll
    for (int a = 0; a < 8; ++a)
#pragma unroll
        for (int c = 0; c < 4; ++c)
            acc[a][c] = (f32x4){0.f, 0.f, 0.f, 0.f};

    float av[16], bv[16];
    auto stage_load = [&](int kt) {
        const float* pa = aPtr + kt * 32;
        float4 t0 = *(const float4*)(pa);
        float4 t1 = *(const float4*)(pa + 4);
        float4 t2 = *(const float4*)(pa + 8);
        float4 t3 = *(const float4*)(pa + 12);
        av[0]=t0.x;  av[1]=t0.y;  av[2]=t0.z;  av[3]=t0.w;
        av[4]=t1.x;  av[5]=t1.y;  av[6]=t1.z;  av[7]=t1.w;
        av[8]=t2.x;  av[9]=t2.y;  av[10]=t2.z; av[11]=t2.w;
        av[12]=t3.x; av[13]=t3.y; av[14]=t3.z; av[15]=t3.w;
        const float* pb = bPtr + (size_t)kt * 32 * N_SZ;
#pragma unroll
        for (int r = 0; r < 16; ++r) bv[r] = pb[(size_t)r * N_SZ];
    };
    auto stage_write = [&](int slot) {
        short* qAh = &Ah_s[slot][0]; short* qAl = &Al_s[slot][0];
        short* qBh = &Bh_s[slot][0]; short* qBl = &Bl_s[slot][0];
        uint4 h, l;
        split2(av[0],  av[1],  h.x, l.x); split2(av[2],  av[3],  h.y, l.y);
        split2(av[4],  av[5],  h.z, l.z); split2(av[6],  av[7],  h.w, l.w);
        *(uint4*)&qAh[wo0] = h; *(uint4*)&qAl[wo0] = l;
        split2(av[8],  av[9],  h.x, l.x); split2(av[10], av[11], h.y, l.y);
        split2(av[12], av[13], h.z, l.z); split2(av[14], av[15], h.w, l.w);
        *(uint4*)&qAh[wo1] = h; *(uint4*)&qAl[wo1] = l;
        split2(bv[0],  bv[1],  h.x, l.x); split2(bv[2],  bv[3],  h.y, l.y);
        split2(bv[4],  bv[5],  h.z, l.z); split2(bv[6],  bv[7],  h.w, l.w);
        *(uint4*)&qBh[wo0] = h; *(uint4*)&qBl[wo0] = l;
        split2(bv[8],  bv[9],  h.x, l.x); split2(bv[10], bv[11], h.y, l.y);
        split2(bv[12], bv[13], h.z, l.z); split2(bv[14], bv[15], h.w, l.w);
        *(uint4*)&qBh[wo1] = h; *(uint4*)&qBl[wo1] = l;
    };

    // ---- prologue: stage tile 0 synchronously into slot 0 ----
    stage_load(0);
    stage_write(0);
    __syncthreads();

    for (int t = 0; t < 16; ++t) {
        const int s = t & 1;
        const short* pAh = &Ah_s[s][0]; const short* pAl = &Al_s[s][0];
        const short* pBh = &Bh_s[s][0]; const short* pBl = &Bl_s[s][0];

        // ---- 1. issue next-tile global loads (consumed at step 3) ----
        if (t < 15) stage_load(t + 1);
        __builtin_amdgcn_sched_barrier(0);

        // ---- 2. B fragments (held across the tile) + ms 0..5 ----
        bf16x8 Bf_h[4], Bf_l[4];
#pragma unroll
        for (int ns = 0; ns < 4; ++ns) {
            const int o = (wc * 64 + ns * 16 + lm) * 32 + fpos8;
            Bf_h[ns] = *(const bf16x8*)&pBh[o];
            Bf_l[ns] = *(const bf16x8*)&pBl[o];
        }
#pragma unroll
        for (int ms = 0; ms < 6; ++ms) {
            const int o = (wr * 128 + ms * 16 + lm) * 32 + fpos8;
            const bf16x8 Af_h = *(const bf16x8*)&pAh[o];
            const bf16x8 Af_l = *(const bf16x8*)&pAl[o];
            __builtin_amdgcn_s_setprio(1);
#pragma unroll
            for (int ns = 0; ns < 4; ++ns) {
                acc[ms][ns] = __builtin_amdgcn_mfma_f32_16x16x32_bf16(Af_h, Bf_h[ns], acc[ms][ns], 0, 0, 0);
                acc[ms][ns] = __builtin_amdgcn_mfma_f32_16x16x32_bf16(Af_h, Bf_l[ns], acc[ms][ns], 0, 0, 0);
                acc[ms][ns] = __builtin_amdgcn_mfma_f32_16x16x32_bf16(Af_l, Bf_h[ns], acc[ms][ns], 0, 0, 0);
            }
            __builtin_amdgcn_s_setprio(0);
        }
        __builtin_amdgcn_sched_barrier(0);

        // ---- 3. split + write tile t+1 into the other slot ----
        if (t < 15) stage_write(s ^ 1);
        __builtin_amdgcn_sched_barrier(0);

        // ---- 4. ms 6..7 ----
#pragma unroll
        for (int ms = 6; ms < 8; ++ms) {
            const int o = (wr * 128 + ms * 16 + lm) * 32 + fpos8;
            const bf16x8 Af_h = *(const bf16x8*)&pAh[o];
            const bf16x8 Af_l = *(const bf16x8*)&pAl[o];
            __builtin_amdgcn_s_setprio(1);
#pragma unroll
            for (int ns = 0; ns < 4; ++ns) {
                acc[ms][ns] = __builtin_amdgcn_mfma_f32_16x16x32_bf16(Af_h, Bf_h[ns], acc[ms][ns], 0, 0, 0);
                acc[ms][ns] = __builtin_amdgcn_mfma_f32_16x16x32_bf16(Af_h, Bf_l[ns], acc[ms][ns], 0, 0, 0);
                acc[ms][ns] = __builtin_amdgcn_mfma_f32_16x16x32_bf16(Af_l, Bf_h[ns], acc[ms][ns], 0, 0, 0);
            }
            __builtin_amdgcn_s_setprio(0);
        }
        __builtin_amdgcn_sched_barrier(0);

        // ---- 5. one barrier per tile: writes visible, slot swap ----
        __syncthreads();
    }

    // ---- write C: D layout col=lane&15, row=quad*4+reg (verified R5/R6) ----
#pragma unroll
    for (int ms = 0; ms < 8; ++ms) {
        const int rowb = m0 + wr * 128 + ms * 16 + quad * 4;
#pragma unroll
        for (int ns = 0; ns < 4; ++ns) {
            const int col = n0 + wc * 64 + ns * 16 + lm;
#pragma unroll
            for (int r = 0; r < 4; ++r)
                fW[((size_t)(rowb + r) * I_SZ + i) * N_SZ + col] = acc[ms][ns][r];
        }
    }
}

// ---------------------------------------------------------------------------
// Kernel 2: routing via Gram matrices (unchanged — near floor).
// ---------------------------------------------------------------------------
__global__ __launch_bounds__(1024) void routing_kernel(
    const float* __restrict__ fW,  // [B, I, N]
    const float* __restrict__ p,   // [B, I]
    float* __restrict__ c_out,     // [B, J, E]
    float* __restrict__ r_out)     // [B, I, J]
{
    const int b   = blockIdx.x;
    const int tid = threadIdx.x;
    const int j   = tid >> 4;      // 0..63
    const int sub = tid & 15;      // e-chunk [sub*8, sub*8+8)

    __shared__ float G_sh[64][49];
    __shared__ float s_sh[64][9];
    __shared__ float w_sh[2][64][9];
    __shared__ float p_sh[8];

    if (tid < I_SZ) p_sh[tid] = p[(size_t)b * I_SZ + tid];

    float4 fw[I_SZ][2];
    const float* base = fW + (size_t)b * I_SZ * N_SZ + j * E_SZ + sub * 8;
#pragma unroll
    for (int i = 0; i < I_SZ; ++i) {
        fw[i][0] = *(const float4*)(base + (size_t)i * N_SZ);
        fw[i][1] = *(const float4*)(base + (size_t)i * N_SZ + 4);
    }

    // ---- Phase 1: Gram + row sums (reduce over 16 sub-lanes) ----
#pragma unroll
    for (int i = 0; i < I_SZ; ++i) {
        float s = fw[i][0].x + fw[i][0].y + fw[i][0].z + fw[i][0].w
                + fw[i][1].x + fw[i][1].y + fw[i][1].z + fw[i][1].w;
        s += __shfl_xor(s, 1); s += __shfl_xor(s, 2);
        s += __shfl_xor(s, 4); s += __shfl_xor(s, 8);
        if (sub == 0) s_sh[j][i] = s;
#pragma unroll
        for (int i2 = i; i2 < I_SZ; ++i2) {
            float g = fw[i][0].x * fw[i2][0].x + fw[i][0].y * fw[i2][0].y
                    + fw[i][0].z * fw[i2][0].z + fw[i][0].w * fw[i2][0].w
                    + fw[i][1].x * fw[i2][1].x + fw[i][1].y * fw[i2][1].y
                    + fw[i][1].z * fw[i2][1].z + fw[i][1].w * fw[i2][1].w;
            g += __shfl_xor(g, 1); g += __shfl_xor(g, 2);
            g += __shfl_xor(g, 4); g += __shfl_xor(g, 8);
            if (sub == 0) { G_sh[j][i * 7 + i2] = g; G_sh[j][i2 * 7 + i] = g; }
        }
    }
    __syncthreads();

    // ---- Phase 2: 10 iterations on the 7x7 system ----
    for (int t = 0; t < ITERS; ++t) {
        if (tid < I_SZ * 64) {                 // waves 0..6
            const int ii = tid >> 6;
            const int jj = tid & 63;
            float l;
            if (t == 0) {
                l = s_sh[jj][ii];              // c0 = ones
            } else {
                const int rb = t & 1;
                l = 0.f;
#pragma unroll
                for (int i2 = 0; i2 < I_SZ; ++i2)
                    l = fmaf(w_sh[rb][jj][i2], G_sh[jj][ii * 7 + i2], l);
            }
            float mx = l;
#pragma unroll
            for (int off = 32; off > 0; off >>= 1)
                mx = fmaxf(mx, __shfl_xor(mx, off));
            float ex = __expf(l - mx);
            float sm = ex;
#pragma unroll
            for (int off = 32; off > 0; off >>= 1)
                sm += __shfl_xor(sm, off);
            float r = ex / sm;
            if (t == ITERS - 1)
                r_out[(size_t)b * (I_SZ * J_SZ) + ii * 64 + jj] = r;
            w_sh[(t + 1) & 1][jj][ii] = p_sh[ii] * r;
        }
        __syncthreads();
    }

    // ---- Phase 3: c from registers ----
    float4 a0 = make_float4(0.f, 0.f, 0.f, 0.f);
    float4 a1 = make_float4(0.f, 0.f, 0.f, 0.f);
#pragma unroll
    for (int i = 0; i < I_SZ; ++i) {
        float wv = w_sh[ITERS & 1][j][i];
        a0.x = fmaf(wv, fw[i][0].x, a0.x); a0.y = fmaf(wv, fw[i][0].y, a0.y);
        a0.z = fmaf(wv, fw[i][0].z, a0.z); a0.w = fmaf(wv, fw[i][0].w, a0.w);
        a1.x = fmaf(wv, fw[i][1].x, a1.x); a1.y = fmaf(wv, fw[i][1].y, a1.y);
        a1.z = fmaf(wv, fw[i][1].z, a1.z); a1.w = fmaf(wv, fw[i][1].w, a1.w);
    }
    float* dst = c_out + (size_t)b * N_SZ + j * E_SZ + sub * 8;
    *(float4*)(dst)     = a0;
    *(float4*)(dst + 4) = a1;
}

extern "C" void kernel_launch(void* const* d_in, const int* in_sizes, int n_in,
                              void* d_out, int out_size, void* d_ws, size_t ws_size,
                              hipStream_t stream) {
    const float* f = (const float*)d_in[0];   // [512,7,512]
    const float* p = (const float*)d_in[1];   // [512,7]
    const float* W = (const float*)d_in[2];   // [7,512,64,128]
    float* out = (float*)d_out;               // c (512*64*128) then r (512*7*64)
    float* fW  = (float*)d_ws;                // 117.4 MB scratch

    vote_gemm_mfma<<<dim3(N_SZ / 256, B_SZ / 256, I_SZ), 512, 0, stream>>>(f, W, fW);
    routing_kernel<<<B_SZ, 1024, 0, stream>>>(fW, p, out, out + (size_t)B_SZ * N_SZ);
}